// Round 11
// baseline (865.890 us; speedup 1.0000x reference)
//
#include <hip/hip_runtime.h>
#include <stdint.h>

// SpMM: COO sparse A (16384x16384, 1,048,576 nnz) @ dense B (16384x256) -> out (16384x256)
// CSR-build + col-quartered bf16 SpMM.
//
// Round-11: SELF-IDENTIFIED XCD binding. R8/R10's partial wins both relied on
// the unverified blockIdx%8->XCD round-robin; this round each block reads its
// physical XCD via s_getreg(HW_REG_XCC_ID) (m09-verified) and takes work for
// its OWN XCD from per-XCD atomic ticket queues, stealing from other queues
// when drained (correctness independent of dispatch placement / XCC_ID value).
// Also: scatter uses nontemporal STORES (kills the 50MB RMW read-for-ownership
// fetch seen in R10). spmm quarter = xcd>>1 -> 2MB bf16 B-slice per XCD L2.

#define M_ROWS 16384
#define NNZ_C  1048576
#define NCOL   256
#define NSHARD 8
#define SHARD_ROWS 2048            // M_ROWS / NSHARD
#define CHUNKS 256                 // nnz chunks; CHUNK_NNZ = NNZ_C/CHUNKS = 4096
#define RB_PER_Q 4096              // row-blocks (4 rows) per col-quarter

typedef int vint2 __attribute__((ext_vector_type(2)));

__device__ __forceinline__ float bf16_lo(unsigned int u) { return __uint_as_float(u << 16); }
__device__ __forceinline__ float bf16_hi(unsigned int u) { return __uint_as_float(u & 0xffff0000u); }

__device__ __forceinline__ unsigned int get_xcd() {
    unsigned int x;
    asm("s_getreg_b32 %0, hwreg(HW_REG_XCC_ID)" : "=s"(x));
    return x & 7u;
}

// ---------------- phase 0: B fp32 -> bf16 (RNE), 8 elems/thread ----------------
__global__ __launch_bounds__(256) void bconv_kernel(const float4* __restrict__ Bf,
                                                    uint4* __restrict__ Bh) {
    const int i = blockIdx.x * 256 + threadIdx.x;      // 524288 threads
    const float4 a = Bf[i * 2];
    const float4 b = Bf[i * 2 + 1];
    unsigned int w[8];
    const float src[8] = {a.x, a.y, a.z, a.w, b.x, b.y, b.z, b.w};
#pragma unroll
    for (int k = 0; k < 8; ++k) {
        unsigned int bits = __float_as_uint(src[k]);
        w[k] = (bits + 0x7fffu + ((bits >> 16) & 1u)) >> 16;   // RNE bf16
    }
    Bh[i] = make_uint4(w[0] | (w[1] << 16), w[2] | (w[3] << 16),
                       w[4] | (w[5] << 16), w[6] | (w[7] << 16));
}

// ---------------- phase 1: histogram, self-ID XCD sharding + stealing ----------------
__global__ __launch_bounds__(256) void hist_persist_kernel(const int* __restrict__ idx,
                                                           unsigned int* __restrict__ counts,
                                                           unsigned int* __restrict__ tickets) {
    const unsigned int myx = get_xcd();
    __shared__ unsigned int s_t;
    for (int sq = 0; sq < NSHARD; ++sq) {
        const unsigned int shard = (myx + sq) & 7u;      // own shard first, then steal
        const int rlo = (int)shard * SHARD_ROWS;
        for (;;) {
            __syncthreads();
            if (threadIdx.x == 0) s_t = atomicAdd(&tickets[shard], 1u);
            __syncthreads();
            const unsigned int chunk = s_t;
            if (chunk >= CHUNKS) break;
#pragma unroll
            for (int k = 0; k < 4; ++k) {
                const int i4 = (int)chunk * 1024 + k * 256 + (int)threadIdx.x;
                const int4 r4 = ((const int4*)idx)[i4];
                if ((unsigned)(r4.x - rlo) < SHARD_ROWS) atomicAdd(&counts[r4.x], 1u);
                if ((unsigned)(r4.y - rlo) < SHARD_ROWS) atomicAdd(&counts[r4.y], 1u);
                if ((unsigned)(r4.z - rlo) < SHARD_ROWS) atomicAdd(&counts[r4.z], 1u);
                if ((unsigned)(r4.w - rlo) < SHARD_ROWS) atomicAdd(&counts[r4.w], 1u);
            }
        }
    }
}

// ---------------- phase 2: exclusive scan (1 block, 1024 thr x 16 bins) ----------------
__global__ __launch_bounds__(1024) void scan_kernel(const unsigned int* __restrict__ counts,
                                                    unsigned int* __restrict__ offsets,
                                                    unsigned int* __restrict__ cursor) {
    __shared__ unsigned int lds[1024];
    const int t = threadIdx.x;
    const uint4* c4 = (const uint4*)counts;
    uint4 L[4];
#pragma unroll
    for (int k = 0; k < 4; ++k) L[k] = c4[t * 4 + k];
    unsigned int local[16];
#pragma unroll
    for (int k = 0; k < 4; ++k) {
        local[k * 4 + 0] = L[k].x;
        local[k * 4 + 1] = L[k].y;
        local[k * 4 + 2] = L[k].z;
        local[k * 4 + 3] = L[k].w;
    }
    unsigned int sum = 0;
#pragma unroll
    for (int i = 0; i < 16; ++i) sum += local[i];
    lds[t] = sum;
    __syncthreads();
    for (int off = 1; off < 1024; off <<= 1) {
        unsigned int v = (t >= off) ? lds[t - off] : 0u;
        __syncthreads();
        lds[t] += v;
        __syncthreads();
    }
    unsigned int base = lds[t] - sum;
#pragma unroll
    for (int i = 0; i < 16; ++i) {
        offsets[t * 16 + i] = base;
        cursor[t * 16 + i]  = base;
        base += local[i];
    }
    if (t == 1023) offsets[M_ROWS] = lds[1023];
}

// ---------------- phase 3: scatter, self-ID XCD sharding + stealing, nt stores ----------------
__global__ __launch_bounds__(256) void scatter_persist_kernel(const int* __restrict__ idx,
                                                              const float* __restrict__ vals,
                                                              unsigned int* __restrict__ cursor,
                                                              int2* __restrict__ pairs,
                                                              unsigned int* __restrict__ tickets) {
    const unsigned int myx = get_xcd();
    __shared__ unsigned int s_t;
    for (int sq = 0; sq < NSHARD; ++sq) {
        const unsigned int shard = (myx + sq) & 7u;
        const int rlo = (int)shard * SHARD_ROWS;
        for (;;) {
            __syncthreads();
            if (threadIdx.x == 0) s_t = atomicAdd(&tickets[shard], 1u);
            __syncthreads();
            const unsigned int chunk = s_t;
            if (chunk >= CHUNKS) break;
#pragma unroll
            for (int k = 0; k < 4; ++k) {
                const int i4 = (int)chunk * 1024 + k * 256 + (int)threadIdx.x;
                const int4   r4 = ((const int4*)idx)[i4];
                const int4   c4 = ((const int4*)(idx + NNZ_C))[i4];
                const float4 v4 = ((const float4*)vals)[i4];
                unsigned int p;
                vint2 pr;
                if ((unsigned)(r4.x - rlo) < SHARD_ROWS) {
                    p = atomicAdd(&cursor[r4.x], 1u);
                    pr.x = c4.x; pr.y = __float_as_int(v4.x);
                    __builtin_nontemporal_store(pr, ((vint2*)pairs) + p);
                }
                if ((unsigned)(r4.y - rlo) < SHARD_ROWS) {
                    p = atomicAdd(&cursor[r4.y], 1u);
                    pr.x = c4.y; pr.y = __float_as_int(v4.y);
                    __builtin_nontemporal_store(pr, ((vint2*)pairs) + p);
                }
                if ((unsigned)(r4.z - rlo) < SHARD_ROWS) {
                    p = atomicAdd(&cursor[r4.z], 1u);
                    pr.x = c4.z; pr.y = __float_as_int(v4.z);
                    __builtin_nontemporal_store(pr, ((vint2*)pairs) + p);
                }
                if ((unsigned)(r4.w - rlo) < SHARD_ROWS) {
                    p = atomicAdd(&cursor[r4.w], 1u);
                    pr.x = c4.w; pr.y = __float_as_int(v4.w);
                    __builtin_nontemporal_store(pr, ((vint2*)pairs) + p);
                }
            }
        }
    }
}

// ---------------- phase 4: col-quartered SpMM, self-ID quarter + stealing ----------------
__global__ __launch_bounds__(256) void spmm_persist_kernel(const unsigned int* __restrict__ offsets,
                                                           const int2* __restrict__ pairs,
                                                           const unsigned short* __restrict__ Bh,
                                                           float* __restrict__ out,
                                                           unsigned int* __restrict__ tickets) {
    const unsigned int myx = get_xcd();
    const int lane = threadIdx.x & 63;
    const int g    = lane >> 3;                  // nnz sub-group 0..7
    const int sub  = lane & 7;                   // 8 cols of the quarter
    const uint4* __restrict__ B16 = (const uint4*)Bh;   // bf16 row = 512B = 32 uint4
    __shared__ unsigned int s_t;

    for (int qq = 0; qq < 4; ++qq) {
        const unsigned int h = ((myx >> 1) + qq) & 3u;   // own quarter first, then steal
        for (;;) {
            __syncthreads();
            if (threadIdx.x == 0) s_t = atomicAdd(&tickets[h], 1u);
            __syncthreads();
            const unsigned int rb = s_t;
            if (rb >= RB_PER_Q) break;

            const int row = (int)rb * 4 + ((int)threadIdx.x >> 6);
            unsigned int beg = __builtin_amdgcn_readfirstlane(offsets[row]);
            unsigned int end = __builtin_amdgcn_readfirstlane(offsets[row + 1]);

            float acc[8] = {0.f, 0.f, 0.f, 0.f, 0.f, 0.f, 0.f, 0.f};
            for (unsigned int base_p = beg; base_p < end; base_p += 64) {
                const unsigned int p = base_p + lane;
                int pc = 0, pv = 0;
                if (p < end) {
                    // nt: 4x-replicated read-once stream; keep out of the B-resident L2
                    const vint2 pr = __builtin_nontemporal_load(((const vint2*)pairs) + p);
                    pc = pr.x;
                    pv = pr.y;
                }
#pragma unroll
                for (int j = 0; j < 64; j += 8) {
                    const int   c = __shfl(pc, j + g, 64);
                    const float v = __int_as_float(__shfl(pv, j + g, 64));
                    const uint4 b = B16[(size_t)c * 32 + h * 8 + sub];
                    acc[0] += v * bf16_lo(b.x);
                    acc[1] += v * bf16_hi(b.x);
                    acc[2] += v * bf16_lo(b.y);
                    acc[3] += v * bf16_hi(b.y);
                    acc[4] += v * bf16_lo(b.z);
                    acc[5] += v * bf16_hi(b.z);
                    acc[6] += v * bf16_lo(b.w);
                    acc[7] += v * bf16_hi(b.w);
                }
            }
#pragma unroll
            for (int k = 0; k < 8; ++k) {
                acc[k] += __shfl_xor(acc[k], 8, 64);
                acc[k] += __shfl_xor(acc[k], 16, 64);
                acc[k] += __shfl_xor(acc[k], 32, 64);
            }
            if (g == 0) {                        // lanes 0..7 store 256B (full lines)
                float* o = out + (size_t)row * NCOL + h * 64 + sub * 8;
                *(float4*)(o)     = make_float4(acc[0], acc[1], acc[2], acc[3]);
                *(float4*)(o + 4) = make_float4(acc[4], acc[5], acc[6], acc[7]);
            }
        }
    }
}

// ---------------- fp32 spmm (fallback tier 1) ----------------
__global__ __launch_bounds__(256) void spmm_csr_kernel(const unsigned int* __restrict__ offsets,
                                                       const int2* __restrict__ pairs,
                                                       const float* __restrict__ B,
                                                       float* __restrict__ out) {
    const int row  = blockIdx.x * 4 + (threadIdx.x >> 6);
    const int lane = threadIdx.x & 63;
    unsigned int beg = __builtin_amdgcn_readfirstlane(offsets[row]);
    unsigned int end = __builtin_amdgcn_readfirstlane(offsets[row + 1]);
    const float4* __restrict__ B4 = (const float4*)B;
    float4 acc = make_float4(0.f, 0.f, 0.f, 0.f);
    for (unsigned int base_p = beg; base_p < end; base_p += 64) {
        const unsigned int p = base_p + lane;
        int pc = 0, pv = 0;
        if (p < end) { int2 pr = pairs[p]; pc = pr.x; pv = pr.y; }
#pragma unroll 8
        for (int j = 0; j < 64; ++j) {
            const int   c = __builtin_amdgcn_readlane(pc, j);
            const float v = __int_as_float(__builtin_amdgcn_readlane(pv, j));
            const float4 b = B4[(size_t)c * 64 + lane];
            acc.x += v * b.x; acc.y += v * b.y; acc.z += v * b.z; acc.w += v * b.w;
        }
    }
    ((float4*)out)[(size_t)row * 64 + lane] = acc;
}

// ---------------- atomic fallback (tier 2) ----------------
__global__ __launch_bounds__(256) void spmm_atomic_kernel(
    const float* __restrict__ vals, const int* __restrict__ idx,
    const float* __restrict__ B, float* __restrict__ out) {
    const int wave = (int)(blockIdx.x * 4 + (threadIdx.x >> 6));
    const int lane = (int)(threadIdx.x & 63);
    if (wave >= NNZ_C) return;
    const int r = idx[wave];
    const int c = idx[NNZ_C + wave];
    const float v = vals[wave];
    const float* brow = B + (size_t)c * NCOL;
    float* orow = out + (size_t)r * NCOL;
#pragma unroll
    for (int k = 0; k < 4; ++k) {
        const int col = lane + 64 * k;
        atomicAdd(&orow[col], v * brow[col]);
    }
}

extern "C" void kernel_launch(void* const* d_in, const int* in_sizes, int n_in,
                              void* d_out, int out_size, void* d_ws, size_t ws_size,
                              hipStream_t stream) {
    const float* A_values  = (const float*)d_in[0];
    const int*   A_indices = (const int*)d_in[1];   // int32 (JAX x64 disabled), [2, NNZ]
    const float* B         = (const float*)d_in[2];
    float*       out       = (float*)d_out;

    // workspace layout
    const size_t OFFSETS_OFF = 0;                               // 16385 u32
    const size_t COUNTS_OFF  = 66560;                           // 16384 u32 (becomes cursor)
    const size_t TICKETS_OFF = COUNTS_OFF + 65536;              // 32 u32 (hist 0..7, scat 8..15, spmm 16..23)
    const size_t PAIRS_OFF   = TICKETS_OFF + 128;               // 8 MB, 16B aligned
    const size_t BH_OFF      = PAIRS_OFF + (size_t)NNZ_C * 8;   // 8 MB bf16 B
    const size_t NEED_FP32   = BH_OFF;
    const size_t NEED_BF16   = BH_OFF + (size_t)M_ROWS * NCOL * 2;

    if (ws_size < NEED_FP32) {
        hipMemsetAsync(d_out, 0, (size_t)out_size * sizeof(float), stream);
        spmm_atomic_kernel<<<NNZ_C / 4, 256, 0, stream>>>(A_values, A_indices, B, out);
        return;
    }

    uint8_t* w = (uint8_t*)d_ws;
    unsigned int*   offsets = (unsigned int*)(w + OFFSETS_OFF);
    unsigned int*   counts  = (unsigned int*)(w + COUNTS_OFF);  // also cursor
    unsigned int*   tickets = (unsigned int*)(w + TICKETS_OFF);
    int2*           pairs   = (int2*)(w + PAIRS_OFF);
    unsigned short* Bh      = (unsigned short*)(w + BH_OFF);

    const bool use_bf16 = (ws_size >= NEED_BF16);

    if (use_bf16) {
        bconv_kernel<<<2048, 256, 0, stream>>>((const float4*)B, (uint4*)Bh);
    }
    // zero counts + all ticket queues in one memset
    hipMemsetAsync(counts, 0, 65536 + 128, stream);
    hist_persist_kernel<<<2048, 256, 0, stream>>>(A_indices, counts, tickets);
    scan_kernel<<<1, 1024, 0, stream>>>(counts, offsets, counts /*cursor*/);
    scatter_persist_kernel<<<2048, 256, 0, stream>>>(A_indices, A_values, counts, pairs,
                                                     tickets + 8);

    if (use_bf16) {
        spmm_persist_kernel<<<4096, 256, 0, stream>>>(offsets, pairs, Bh, out, tickets + 16);
    } else {
        spmm_csr_kernel<<<M_ROWS / 4, 256, 0, stream>>>(offsets, pairs, B, out);
    }
}

// Round 12
// 116.629 us; speedup vs baseline: 7.4243x; 7.4243x over previous
//
#include <hip/hip_runtime.h>
#include <stdint.h>

// SpMM: COO sparse A (16384x16384, 1,048,576 nnz) @ dense B (16384x256) -> out (16384x256)
// Round-12: two-level bucket counting-sort replaces the partial-line scatter.
//   R11 lessons: (a) quarter-per-XCD B-slices ARE L2-resident (FETCH 404->29MB),
//   (b) per-work-item ticket atomics + barrier drains serialize waves (379us).
//   So: spmm reverts to R10's static quartered kernel (best total), and the
//   CSR build becomes: A0 bucket-hist -> tinyscan -> passA (bucket partition,
//   dense ~256B region writes, row packed into meta bits) -> passB (per-bucket
//   LDS counting sort, full-line writes, emits offsets). Bucketed intermediate
//   lives in d_out's first 8MB (spmm overwrites d_out afterwards).
//   hist_kernel/scan_kernel deleted.

#define M_ROWS 16384
#define NNZ_C  1048576
#define NCOL   256
#define NBUCK  128                 // buckets of 128 rows
#define BROWS  128
#define ACHUNKS 256                // passA/A0 blocks; 4096 nnz each

typedef int vint2 __attribute__((ext_vector_type(2)));

__device__ __forceinline__ float bf16_lo(unsigned int u) { return __uint_as_float(u << 16); }
__device__ __forceinline__ float bf16_hi(unsigned int u) { return __uint_as_float(u & 0xffff0000u); }

// ---------------- phase 0: B fp32 -> bf16 (RNE), 8 elems/thread ----------------
__global__ __launch_bounds__(256) void bconv_kernel(const float4* __restrict__ Bf,
                                                    uint4* __restrict__ Bh) {
    const int i = blockIdx.x * 256 + threadIdx.x;      // 524288 threads
    const float4 a = Bf[i * 2];
    const float4 b = Bf[i * 2 + 1];
    unsigned int w[8];
    const float src[8] = {a.x, a.y, a.z, a.w, b.x, b.y, b.z, b.w};
#pragma unroll
    for (int k = 0; k < 8; ++k) {
        unsigned int bits = __float_as_uint(src[k]);
        w[k] = (bits + 0x7fffu + ((bits >> 16) & 1u)) >> 16;   // RNE bf16
    }
    Bh[i] = make_uint4(w[0] | (w[1] << 16), w[2] | (w[3] << 16),
                       w[4] | (w[5] << 16), w[6] | (w[7] << 16));
}

// ---------------- A0: bucket histogram (LDS -> 128 global adds/block) ----------------
__global__ __launch_bounds__(256) void bucket_hist_kernel(const int* __restrict__ idx,
                                                          unsigned int* __restrict__ gbucket) {
    __shared__ unsigned int bcnt[NBUCK];
    if (threadIdx.x < NBUCK) bcnt[threadIdx.x] = 0u;
    __syncthreads();
#pragma unroll
    for (int k = 0; k < 4; ++k) {
        const int i4 = blockIdx.x * 1024 + k * 256 + threadIdx.x;
        const int4 r4 = ((const int4*)idx)[i4];
        atomicAdd(&bcnt[r4.x >> 7], 1u);
        atomicAdd(&bcnt[r4.y >> 7], 1u);
        atomicAdd(&bcnt[r4.z >> 7], 1u);
        atomicAdd(&bcnt[r4.w >> 7], 1u);
    }
    __syncthreads();
    if (threadIdx.x < NBUCK && bcnt[threadIdx.x] > 0u)
        atomicAdd(&gbucket[threadIdx.x], bcnt[threadIdx.x]);
}

// ---------------- tinyscan: 128-wide exclusive scan -> bases & cursors ----------------
__global__ __launch_bounds__(128) void bucket_scan_kernel(const unsigned int* __restrict__ gbucket,
                                                          unsigned int* __restrict__ bbase,   // [129]
                                                          unsigned int* __restrict__ gcursor, // [128]
                                                          unsigned int* __restrict__ offsets) {
    __shared__ unsigned int temp[NBUCK];
    const int t = threadIdx.x;
    const unsigned int own = gbucket[t];
    temp[t] = own;
    __syncthreads();
    for (int off = 1; off < NBUCK; off <<= 1) {
        unsigned int v = (t >= off) ? temp[t - off] : 0u;
        __syncthreads();
        temp[t] += v;
        __syncthreads();
    }
    const unsigned int excl = temp[t] - own;
    bbase[t]   = excl;
    gcursor[t] = excl;
    if (t == NBUCK - 1) {
        bbase[NBUCK]    = temp[t];      // == NNZ
        offsets[M_ROWS] = temp[t];
    }
}

// ---------------- passA: bucket partition with dense region writes ----------------
// entry meta = (row & 127) << 14 | col  (col < 16384 fits 14 bits)
__global__ __launch_bounds__(256) void bucket_part_kernel(const int* __restrict__ idx,
                                                          const float* __restrict__ vals,
                                                          unsigned int* __restrict__ gcursor,
                                                          int2* __restrict__ bucketed) {
    __shared__ unsigned int cnt[NBUCK], cur[NBUCK], gb[NBUCK];
    if (threadIdx.x < NBUCK) { cnt[threadIdx.x] = 0u; cur[threadIdx.x] = 0u; }
    __syncthreads();

    int4 r4[4], c4[4];
    float4 v4[4];
#pragma unroll
    for (int k = 0; k < 4; ++k) {
        const int i4 = blockIdx.x * 1024 + k * 256 + threadIdx.x;
        r4[k] = ((const int4*)idx)[i4];
        c4[k] = ((const int4*)(idx + NNZ_C))[i4];
        v4[k] = ((const float4*)vals)[i4];
        atomicAdd(&cnt[r4[k].x >> 7], 1u);
        atomicAdd(&cnt[r4[k].y >> 7], 1u);
        atomicAdd(&cnt[r4[k].z >> 7], 1u);
        atomicAdd(&cnt[r4[k].w >> 7], 1u);
    }
    __syncthreads();
    if (threadIdx.x < NBUCK && cnt[threadIdx.x] > 0u)
        gb[threadIdx.x] = atomicAdd(&gcursor[threadIdx.x], cnt[threadIdx.x]);
    __syncthreads();

#pragma unroll
    for (int k = 0; k < 4; ++k) {
        const int  rr[4] = {r4[k].x, r4[k].y, r4[k].z, r4[k].w};
        const int  cc[4] = {c4[k].x, c4[k].y, c4[k].z, c4[k].w};
        const float vv[4] = {v4[k].x, v4[k].y, v4[k].z, v4[k].w};
#pragma unroll
        for (int e = 0; e < 4; ++e) {
            const int b = rr[e] >> 7;
            const unsigned int pos = gb[b] + atomicAdd(&cur[b], 1u);
            bucketed[pos] = make_int2(((rr[e] & 127) << 14) | cc[e], __float_as_int(vv[e]));
        }
    }
}

// ---------------- passB: per-bucket LDS counting sort -> exact CSR + offsets ----------------
__global__ __launch_bounds__(256) void bucket_sort_kernel(const unsigned int* __restrict__ bbase,
                                                          const int2* __restrict__ bucketed,
                                                          int2* __restrict__ pairs,
                                                          unsigned int* __restrict__ offsets) {
    __shared__ unsigned int rcnt[BROWS], rbase[BROWS], rcur[BROWS], temp[BROWS];
    const int b = blockIdx.x;
    const unsigned int base = bbase[b];
    const unsigned int endb = bbase[b + 1];
    const int n = (int)(endb - base);
    const int t = threadIdx.x;

    if (t < BROWS) { rcnt[t] = 0u; rcur[t] = 0u; }
    __syncthreads();

    // pass 1: per-row histogram (segment is L2-hot for pass 2)
    for (int i = t; i < n; i += 256) {
        const int meta = bucketed[base + i].x;
        atomicAdd(&rcnt[meta >> 14], 1u);
    }
    __syncthreads();

    // exclusive scan of 128 row counts
    if (t < BROWS) temp[t] = rcnt[t];
    __syncthreads();
    for (int off = 1; off < BROWS; off <<= 1) {
        unsigned int v = 0u;
        if (t < BROWS && t >= off) v = temp[t - off];
        __syncthreads();
        if (t < BROWS) temp[t] += v;
        __syncthreads();
    }
    if (t < BROWS) {
        rbase[t] = temp[t] - rcnt[t];
        offsets[b * BROWS + t] = base + rbase[t];
    }
    __syncthreads();

    // pass 2: place (dest segment owned by this block's XCD -> full-line writes)
    for (int i = t; i < n; i += 256) {
        const int2 pr = bucketed[base + i];
        const int rl = pr.x >> 14;
        const unsigned int dst = base + rbase[rl] + atomicAdd(&rcur[rl], 1u);
        pairs[dst] = make_int2(pr.x & 16383, pr.y);
    }
}

// ---------------- spmm: col-quartered bf16, static XCD heuristic (R10 control) ----------------
__global__ __launch_bounds__(256) void spmm_bf16_q_kernel(const unsigned int* __restrict__ offsets,
                                                          const int2* __restrict__ pairs,
                                                          const unsigned short* __restrict__ Bh,
                                                          float* __restrict__ out) {
    const int bid    = blockIdx.x;
    const int xcd    = bid & 7;
    const int slot   = bid >> 3;                 // 0..2047
    const int h      = xcd >> 1;                 // col quarter 0..3
    const int rowblk = (xcd & 1) * 2048 + slot;  // 0..4095
    const int row    = rowblk * 4 + (threadIdx.x >> 6);
    const int lane   = threadIdx.x & 63;
    const int g      = lane >> 3;                // nnz sub-group 0..7
    const int sub    = lane & 7;                 // 8 cols of the quarter

    unsigned int beg = __builtin_amdgcn_readfirstlane(offsets[row]);
    unsigned int end = __builtin_amdgcn_readfirstlane(offsets[row + 1]);

    const uint4* __restrict__ B16 = (const uint4*)Bh;   // bf16 row = 512B = 32 uint4
    float acc[8] = {0.f, 0.f, 0.f, 0.f, 0.f, 0.f, 0.f, 0.f};

    for (unsigned int base_p = beg; base_p < end; base_p += 64) {
        const unsigned int p = base_p + lane;
        int pc = 0, pv = 0;
        if (p < end) {
            // nt: 4x-replicated read-once stream; keep out of the B-resident L2
            const vint2 pr = __builtin_nontemporal_load(((const vint2*)pairs) + p);
            pc = pr.x;
            pv = pr.y;
        }
#pragma unroll
        for (int j = 0; j < 64; j += 8) {
            const int   c = __shfl(pc, j + g, 64);
            const float v = __int_as_float(__shfl(pv, j + g, 64));
            const uint4 b = B16[(size_t)c * 32 + h * 8 + sub];
            acc[0] += v * bf16_lo(b.x);
            acc[1] += v * bf16_hi(b.x);
            acc[2] += v * bf16_lo(b.y);
            acc[3] += v * bf16_hi(b.y);
            acc[4] += v * bf16_lo(b.z);
            acc[5] += v * bf16_hi(b.z);
            acc[6] += v * bf16_lo(b.w);
            acc[7] += v * bf16_hi(b.w);
        }
    }
#pragma unroll
    for (int k = 0; k < 8; ++k) {
        acc[k] += __shfl_xor(acc[k], 8, 64);
        acc[k] += __shfl_xor(acc[k], 16, 64);
        acc[k] += __shfl_xor(acc[k], 32, 64);
    }
    if (g == 0) {                                // lanes 0..7 store 256B (full lines)
        float* o = out + (size_t)row * NCOL + h * 64 + sub * 8;
        *(float4*)(o)     = make_float4(acc[0], acc[1], acc[2], acc[3]);
        *(float4*)(o + 4) = make_float4(acc[4], acc[5], acc[6], acc[7]);
    }
}

// ---------------- atomic fallback (ws too small) ----------------
__global__ __launch_bounds__(256) void spmm_atomic_kernel(
    const float* __restrict__ vals, const int* __restrict__ idx,
    const float* __restrict__ B, float* __restrict__ out) {
    const int wave = (int)(blockIdx.x * 4 + (threadIdx.x >> 6));
    const int lane = (int)(threadIdx.x & 63);
    if (wave >= NNZ_C) return;
    const int r = idx[wave];
    const int c = idx[NNZ_C + wave];
    const float v = vals[wave];
    const float* brow = B + (size_t)c * NCOL;
    float* orow = out + (size_t)r * NCOL;
#pragma unroll
    for (int k = 0; k < 4; ++k) {
        const int col = lane + 64 * k;
        atomicAdd(&orow[col], v * brow[col]);
    }
}

extern "C" void kernel_launch(void* const* d_in, const int* in_sizes, int n_in,
                              void* d_out, int out_size, void* d_ws, size_t ws_size,
                              hipStream_t stream) {
    const float* A_values  = (const float*)d_in[0];
    const int*   A_indices = (const int*)d_in[1];   // int32 (JAX x64 disabled), [2, NNZ]
    const float* B         = (const float*)d_in[2];
    float*       out       = (float*)d_out;

    // workspace layout
    const size_t OFFSETS_OFF = 0;                       // 16385 u32 = 65540 B
    const size_t GBUCKET_OFF = 66560;                   // 128 u32
    const size_t BBASE_OFF   = GBUCKET_OFF + 512;       // 129 u32 (pad to 528)
    const size_t GCURSOR_OFF = BBASE_OFF + 528;         // 128 u32
    const size_t PAIRS_OFF   = 68608;                   // 8 MB, 16B aligned
    const size_t BH_OFF      = PAIRS_OFF + (size_t)NNZ_C * 8;
    const size_t NEEDED      = BH_OFF + (size_t)16384 * NCOL * 2;  // ~16.85 MB

    if (ws_size < NEEDED) {
        hipMemsetAsync(d_out, 0, (size_t)out_size * sizeof(float), stream);
        spmm_atomic_kernel<<<NNZ_C / 4, 256, 0, stream>>>(A_values, A_indices, B, out);
        return;
    }

    uint8_t* w = (uint8_t*)d_ws;
    unsigned int*   offsets = (unsigned int*)(w + OFFSETS_OFF);
    unsigned int*   gbucket = (unsigned int*)(w + GBUCKET_OFF);
    unsigned int*   bbase   = (unsigned int*)(w + BBASE_OFF);
    unsigned int*   gcursor = (unsigned int*)(w + GCURSOR_OFF);
    int2*           pairs   = (int2*)(w + PAIRS_OFF);
    unsigned short* Bh      = (unsigned short*)(w + BH_OFF);
    int2*           bucketed = (int2*)d_out;            // d_out scratch (8MB of 64MB);
                                                        // spmm overwrites d_out afterwards

    bconv_kernel<<<2048, 256, 0, stream>>>((const float4*)B, (uint4*)Bh);
    hipMemsetAsync(gbucket, 0, 512, stream);
    bucket_hist_kernel<<<ACHUNKS, 256, 0, stream>>>(A_indices, gbucket);
    bucket_scan_kernel<<<1, 128, 0, stream>>>(gbucket, bbase, gcursor, offsets);
    bucket_part_kernel<<<ACHUNKS, 256, 0, stream>>>(A_indices, A_values, gcursor, bucketed);
    bucket_sort_kernel<<<NBUCK, 256, 0, stream>>>(bbase, bucketed, pairs, offsets);
    spmm_bf16_q_kernel<<<16384, 256, 0, stream>>>(offsets, pairs, Bh, out);
}

// Round 13
// 110.203 us; speedup vs baseline: 7.8572x; 1.0583x over previous
//
#include <hip/hip_runtime.h>
#include <stdint.h>

// SpMM: COO sparse A (16384x16384, 1,048,576 nnz) @ dense B (16384x256) -> out (16384x256)
// Round-13:
//  (a) spmm: mask tail j-iterations (wave-uniform break at nub=ceil(valid/8)*8).
//      R12 ran all 8 gather-groups per chunk; ~47% of rows have a mostly-empty
//      second chunk -> ~28% of gather instructions were garbage (OOB lanes
//      gathered B row 0). Gather insts 771K -> ~556K.
//  (b) setup consolidation: bconv fused into hist dispatch (disjoint block
//      ranges); tinyscan deleted (part/sort self-scan gbucket in LDS); sort
//      LDS-stages its bucket so pass 2 reads LDS. 7 dispatches -> 5.
// Pipeline: memset(1KB) -> conv+hist -> part -> sort -> spmm.

#define M_ROWS 16384
#define NNZ_C  1048576
#define NCOL   256
#define NBUCK  128                 // buckets of 128 rows
#define BROWS  128
#define ACHUNKS 256                // hist/part chunks; 4096 nnz each
#define SORT_CAP 9216              // LDS stage entries (bucket ~8192 +- 90; 11+ sd margin)

typedef int vint2 __attribute__((ext_vector_type(2)));

__device__ __forceinline__ float bf16_lo(unsigned int u) { return __uint_as_float(u << 16); }
__device__ __forceinline__ float bf16_hi(unsigned int u) { return __uint_as_float(u & 0xffff0000u); }

// ---------------- fused: B fp32->bf16 (blocks 0..2047) + bucket hist (2048..2303) ----------------
__global__ __launch_bounds__(256) void conv_hist_kernel(const float4* __restrict__ Bf,
                                                        uint4* __restrict__ Bh,
                                                        const int* __restrict__ idx,
                                                        unsigned int* __restrict__ gbucket) {
    __shared__ unsigned int bcnt[NBUCK];
    if (blockIdx.x < 2048) {
        const int i = blockIdx.x * 256 + threadIdx.x;      // 524288 threads, 8 elems each
        const float4 a = Bf[i * 2];
        const float4 b = Bf[i * 2 + 1];
        unsigned int w[8];
        const float src[8] = {a.x, a.y, a.z, a.w, b.x, b.y, b.z, b.w};
#pragma unroll
        for (int k = 0; k < 8; ++k) {
            unsigned int bits = __float_as_uint(src[k]);
            w[k] = (bits + 0x7fffu + ((bits >> 16) & 1u)) >> 16;   // RNE bf16
        }
        Bh[i] = make_uint4(w[0] | (w[1] << 16), w[2] | (w[3] << 16),
                           w[4] | (w[5] << 16), w[6] | (w[7] << 16));
    } else {
        const int blk = blockIdx.x - 2048;                 // 0..255
        if (threadIdx.x < NBUCK) bcnt[threadIdx.x] = 0u;
        __syncthreads();
#pragma unroll
        for (int k = 0; k < 4; ++k) {
            const int i4 = blk * 1024 + k * 256 + threadIdx.x;
            const int4 r4 = ((const int4*)idx)[i4];
            atomicAdd(&bcnt[r4.x >> 7], 1u);
            atomicAdd(&bcnt[r4.y >> 7], 1u);
            atomicAdd(&bcnt[r4.z >> 7], 1u);
            atomicAdd(&bcnt[r4.w >> 7], 1u);
        }
        __syncthreads();
        if (threadIdx.x < NBUCK && bcnt[threadIdx.x] > 0u)
            atomicAdd(&gbucket[threadIdx.x], bcnt[threadIdx.x]);
    }
}

// ---------------- passA: bucket partition (self-scan of gbucket; dense region writes) ----------------
// entry meta = (row & 127) << 14 | col  (col < 16384 fits 14 bits)
__global__ __launch_bounds__(256) void bucket_part_kernel(const int* __restrict__ idx,
                                                          const float* __restrict__ vals,
                                                          const unsigned int* __restrict__ gbucket,
                                                          unsigned int* __restrict__ gcursor,
                                                          int2* __restrict__ bucketed) {
    __shared__ unsigned int cnt[NBUCK], cur[NBUCK], gb[NBUCK], stmp[NBUCK];
    const int t = threadIdx.x;
    unsigned int own = 0u;
    if (t < NBUCK) { cnt[t] = 0u; cur[t] = 0u; own = gbucket[t]; stmp[t] = own; }
    __syncthreads();
    // inclusive scan of 128 bucket counts
    for (int off = 1; off < NBUCK; off <<= 1) {
        unsigned int v = (t < NBUCK && t >= off) ? stmp[t - off] : 0u;
        __syncthreads();
        if (t < NBUCK) stmp[t] += v;
        __syncthreads();
    }

    int4 r4[4], c4[4];
    float4 v4[4];
#pragma unroll
    for (int k = 0; k < 4; ++k) {
        const int i4 = blockIdx.x * 1024 + k * 256 + t;
        r4[k] = ((const int4*)idx)[i4];
        c4[k] = ((const int4*)(idx + NNZ_C))[i4];
        v4[k] = ((const float4*)vals)[i4];
        atomicAdd(&cnt[r4[k].x >> 7], 1u);
        atomicAdd(&cnt[r4[k].y >> 7], 1u);
        atomicAdd(&cnt[r4[k].z >> 7], 1u);
        atomicAdd(&cnt[r4[k].w >> 7], 1u);
    }
    __syncthreads();
    if (t < NBUCK && cnt[t] > 0u)
        gb[t] = (stmp[t] - own) + atomicAdd(&gcursor[t], cnt[t]);   // excl base + region
    __syncthreads();

#pragma unroll
    for (int k = 0; k < 4; ++k) {
        const int  rr[4] = {r4[k].x, r4[k].y, r4[k].z, r4[k].w};
        const int  cc[4] = {c4[k].x, c4[k].y, c4[k].z, c4[k].w};
        const float vv[4] = {v4[k].x, v4[k].y, v4[k].z, v4[k].w};
#pragma unroll
        for (int e = 0; e < 4; ++e) {
            const int b = rr[e] >> 7;
            const unsigned int pos = gb[b] + atomicAdd(&cur[b], 1u);
            bucketed[pos] = make_int2(((rr[e] & 127) << 14) | cc[e], __float_as_int(vv[e]));
        }
    }
}

// ---------------- passB: per-bucket LDS counting sort (self-scan; LDS-staged) ----------------
__global__ __launch_bounds__(256) void bucket_sort_kernel(const unsigned int* __restrict__ gbucket,
                                                          const int2* __restrict__ bucketed,
                                                          int2* __restrict__ pairs,
                                                          unsigned int* __restrict__ offsets) {
    __shared__ unsigned int rcnt[BROWS], rbase[BROWS], rcur[BROWS], stmp[BROWS];
    __shared__ unsigned int s_base, s_end;
    __shared__ int2 stage[SORT_CAP];
    const int b = blockIdx.x;
    const int t = threadIdx.x;

    unsigned int own = 0u;
    if (t < NBUCK) { own = gbucket[t]; stmp[t] = own; }
    if (t < BROWS) { rcnt[t] = 0u; rcur[t] = 0u; }
    __syncthreads();
    for (int off = 1; off < NBUCK; off <<= 1) {
        unsigned int v = (t < NBUCK && t >= off) ? stmp[t - off] : 0u;
        __syncthreads();
        if (t < NBUCK) stmp[t] += v;
        __syncthreads();
    }
    if (t == b) { s_base = stmp[t] - own; s_end = stmp[t]; }       // this bucket's range
    if (b == NBUCK - 1 && t == NBUCK - 1) offsets[M_ROWS] = stmp[t];  // == NNZ
    __syncthreads();
    const unsigned int base = s_base;
    const int n = (int)(s_end - s_base);

    // pass 1: load + stage in LDS + per-row histogram
    for (int i = t; i < n; i += 256) {
        const int2 pr = bucketed[base + i];
        if (i < SORT_CAP) stage[i] = pr;
        atomicAdd(&rcnt[pr.x >> 14], 1u);
    }
    __syncthreads();

    // exclusive scan of 128 row counts (reuse stmp)
    if (t < BROWS) stmp[t] = rcnt[t];
    __syncthreads();
    for (int off = 1; off < BROWS; off <<= 1) {
        unsigned int v = (t < BROWS && t >= off) ? stmp[t - off] : 0u;
        __syncthreads();
        if (t < BROWS) stmp[t] += v;
        __syncthreads();
    }
    if (t < BROWS) {
        rbase[t] = stmp[t] - rcnt[t];
        offsets[b * BROWS + t] = base + rbase[t];
    }
    __syncthreads();

    // pass 2: place from LDS (global fallback if bucket exceeded cap — statistically never)
    for (int i = t; i < n; i += 256) {
        const int2 pr = (i < SORT_CAP) ? stage[i] : bucketed[base + i];
        const int rl = pr.x >> 14;
        const unsigned int dst = base + rbase[rl] + atomicAdd(&rcur[rl], 1u);
        pairs[dst] = make_int2(pr.x & 16383, pr.y);
    }
}

// ---------------- spmm: col-quartered bf16, tail-masked gathers ----------------
__global__ __launch_bounds__(256) void spmm_bf16_q_kernel(const unsigned int* __restrict__ offsets,
                                                          const int2* __restrict__ pairs,
                                                          const unsigned short* __restrict__ Bh,
                                                          float* __restrict__ out) {
    const int bid    = blockIdx.x;
    const int xcd    = bid & 7;
    const int slot   = bid >> 3;                 // 0..2047
    const int h      = xcd >> 1;                 // col quarter 0..3
    const int rowblk = (xcd & 1) * 2048 + slot;  // 0..4095
    const int row    = rowblk * 4 + (threadIdx.x >> 6);
    const int lane   = threadIdx.x & 63;
    const int g      = lane >> 3;                // nnz sub-group 0..7
    const int sub    = lane & 7;                 // 8 cols of the quarter

    unsigned int beg = __builtin_amdgcn_readfirstlane(offsets[row]);
    unsigned int end = __builtin_amdgcn_readfirstlane(offsets[row + 1]);

    const uint4* __restrict__ B16 = (const uint4*)Bh;   // bf16 row = 512B = 32 uint4
    float acc[8] = {0.f, 0.f, 0.f, 0.f, 0.f, 0.f, 0.f, 0.f};

    for (unsigned int base_p = beg; base_p < end; base_p += 64) {
        const unsigned int p = base_p + lane;
        int pc = 0, pv = 0;
        if (p < end) {
            // nt: 4x-replicated read-once stream; keep out of the B-resident L2
            const vint2 pr = __builtin_nontemporal_load(((const vint2*)pairs) + p);
            pc = pr.x;
            pv = pr.y;
        }
        const int nub = (int)min(64u, end - base_p);    // valid nnz in this chunk (wave-uniform)
#pragma unroll 8
        for (int j = 0; j < 64; j += 8) {
            if (j >= nub) break;                        // wave-uniform: skip garbage gathers
            const int   c = __shfl(pc, j + g, 64);
            const float v = __int_as_float(__shfl(pv, j + g, 64));
            const uint4 b = B16[(size_t)c * 32 + h * 8 + sub];
            acc[0] += v * bf16_lo(b.x);
            acc[1] += v * bf16_hi(b.x);
            acc[2] += v * bf16_lo(b.y);
            acc[3] += v * bf16_hi(b.y);
            acc[4] += v * bf16_lo(b.z);
            acc[5] += v * bf16_hi(b.z);
            acc[6] += v * bf16_lo(b.w);
            acc[7] += v * bf16_hi(b.w);
        }
    }
#pragma unroll
    for (int k = 0; k < 8; ++k) {
        acc[k] += __shfl_xor(acc[k], 8, 64);
        acc[k] += __shfl_xor(acc[k], 16, 64);
        acc[k] += __shfl_xor(acc[k], 32, 64);
    }
    if (g == 0) {                                // lanes 0..7 store 256B (full lines)
        float* o = out + (size_t)row * NCOL + h * 64 + sub * 8;
        *(float4*)(o)     = make_float4(acc[0], acc[1], acc[2], acc[3]);
        *(float4*)(o + 4) = make_float4(acc[4], acc[5], acc[6], acc[7]);
    }
}

// ---------------- atomic fallback (ws too small) ----------------
__global__ __launch_bounds__(256) void spmm_atomic_kernel(
    const float* __restrict__ vals, const int* __restrict__ idx,
    const float* __restrict__ B, float* __restrict__ out) {
    const int wave = (int)(blockIdx.x * 4 + (threadIdx.x >> 6));
    const int lane = (int)(threadIdx.x & 63);
    if (wave >= NNZ_C) return;
    const int r = idx[wave];
    const int c = idx[NNZ_C + wave];
    const float v = vals[wave];
    const float* brow = B + (size_t)c * NCOL;
    float* orow = out + (size_t)r * NCOL;
#pragma unroll
    for (int k = 0; k < 4; ++k) {
        const int col = lane + 64 * k;
        atomicAdd(&orow[col], v * brow[col]);
    }
}

extern "C" void kernel_launch(void* const* d_in, const int* in_sizes, int n_in,
                              void* d_out, int out_size, void* d_ws, size_t ws_size,
                              hipStream_t stream) {
    const float* A_values  = (const float*)d_in[0];
    const int*   A_indices = (const int*)d_in[1];   // int32 (JAX x64 disabled), [2, NNZ]
    const float* B         = (const float*)d_in[2];
    float*       out       = (float*)d_out;

    // workspace layout
    const size_t OFFSETS_OFF = 0;                       // 16385 u32 = 65540 B
    const size_t GBUCKET_OFF = 66560;                   // 128 u32 = 512 B
    const size_t GCURSOR_OFF = GBUCKET_OFF + 512;       // 128 u32 = 512 B (contiguous memset)
    const size_t PAIRS_OFF   = 68608;                   // 8 MB, 16B aligned
    const size_t BH_OFF      = PAIRS_OFF + (size_t)NNZ_C * 8;
    const size_t NEEDED      = BH_OFF + (size_t)M_ROWS * NCOL * 2;  // ~16.1 MiB

    if (ws_size < NEEDED) {
        hipMemsetAsync(d_out, 0, (size_t)out_size * sizeof(float), stream);
        spmm_atomic_kernel<<<NNZ_C / 4, 256, 0, stream>>>(A_values, A_indices, B, out);
        return;
    }

    uint8_t* w = (uint8_t*)d_ws;
    unsigned int*   offsets = (unsigned int*)(w + OFFSETS_OFF);
    unsigned int*   gbucket = (unsigned int*)(w + GBUCKET_OFF);
    unsigned int*   gcursor = (unsigned int*)(w + GCURSOR_OFF);
    int2*           pairs   = (int2*)(w + PAIRS_OFF);
    unsigned short* Bh      = (unsigned short*)(w + BH_OFF);
    int2*           bucketed = (int2*)d_out;            // d_out scratch (8MB of 64MB);
                                                        // spmm fully overwrites d_out after

    hipMemsetAsync(gbucket, 0, 1024, stream);           // gbucket + gcursor
    conv_hist_kernel<<<2048 + ACHUNKS, 256, 0, stream>>>((const float4*)B, (uint4*)Bh,
                                                         A_indices, gbucket);
    bucket_part_kernel<<<ACHUNKS, 256, 0, stream>>>(A_indices, A_values, gbucket, gcursor,
                                                    bucketed);
    bucket_sort_kernel<<<NBUCK, 256, 0, stream>>>(gbucket, bucketed, pairs, offsets);
    spmm_bf16_q_kernel<<<16384, 256, 0, stream>>>(offsets, pairs, Bh, out);
}